// Round 3
// baseline (1389.970 us; speedup 1.0000x reference)
//
#include <hip/hip_runtime.h>
#include <hip/hip_bf16.h>
#include <stdint.h>

// WeightOnlyInt8Linear: out[m][n] = (sum_k x[m][k]*wq[n][k]) * scale[n] + bias[n]
// M = B*S = 8192, K = 4096, N = 11008.
// HARNESS DTYPES (round-2 finding): reference fp16 tensors are promoted to
// FLOAT32 on device. x f32 [M][K]; wq int32 [N][K]; scale/bias f32 [N];
// OUT is f32 [M][N].
// Structure: 128x128 tile, BK=32, 4 waves, 16x16x32 bf16 MFMA (m97 pattern).
// Both operands converted to bf16 (RNE for x; exact for int8 weights) during
// reg-staged LDS write. Per-channel scale+bias in f32 epilogue.

#define M_DIM 8192
#define N_DIM 11008
#define K_DIM 4096
#define BM 128
#define BN 128
#define BK 32

typedef __attribute__((ext_vector_type(4))) float f32x4;
typedef __attribute__((ext_vector_type(8))) short bf16x8;
typedef __attribute__((ext_vector_type(4))) int i32x4;

__device__ __forceinline__ uint2 pack4_bf16(float f0, float f1, float f2, float f3) {
    union { ushort u[4]; uint2 v; } pk;
    pk.u[0] = __bfloat16_as_ushort(__float2bfloat16(f0));
    pk.u[1] = __bfloat16_as_ushort(__float2bfloat16(f1));
    pk.u[2] = __bfloat16_as_ushort(__float2bfloat16(f2));
    pk.u[3] = __bfloat16_as_ushort(__float2bfloat16(f3));
    return pk.v;
}

extern "C" __global__ __launch_bounds__(256)
void wq8_gemm(const float* __restrict__ X,
              const int* __restrict__ Wq,
              const float* __restrict__ Sc,
              const float* __restrict__ Bi,
              float* __restrict__ Out)
{
    __shared__ __hip_bfloat16 As[BM][BK];   // 8 KB
    __shared__ __hip_bfloat16 Bs[BN][BK];   // 8 KB

    const int tid = threadIdx.x;
    const int w   = tid >> 6;     // wave 0..3
    const int l   = tid & 63;
    const int wr  = w >> 1;       // wave M-half
    const int wc  = w & 1;        // wave N-half
    const int fr  = l & 15;       // fragment row/col
    const int fq  = l >> 4;       // k-chunk

    // XCD-aware swizzle (nwg = 5504 divisible by 8) + GROUP_M=8 supertile map:
    // consecutive wgids share one B-panel across 8 A-panels -> L2/L3 locality.
    const int ntn  = N_DIM / BN;             // 86
    const int nwg  = (M_DIM / BM) * ntn;     // 5504
    const int bid  = (int)blockIdx.x;
    const int wgid = (bid & 7) * (nwg >> 3) + (bid >> 3);
    const int g    = wgid / (8 * ntn);       // 0..7 (exact: 5504/688=8)
    const int rr   = wgid % (8 * ntn);
    const int tm   = g * 8 + (rr & 7);
    const int tn   = rr >> 3;

    // ---- Staging geometry (identical for A and B) ----
    // phase q (0..3): tile row = q*32 + tid/8, cols (tid&7)*4 .. +3
    // 64 lanes x 16B consecutive per phase -> fully coalesced.
    const int srow = tid >> 3;       // 0..31
    const int scol = (tid & 7) * 4;  // 0,4,..,28
    const float* a_g = X  + (size_t)(tm * BM + srow) * K_DIM + scol;
    const int*   b_g = Wq + (size_t)(tn * BN + srow) * K_DIM + scol;

    f32x4 acc[4][4];
    #pragma unroll
    for (int m = 0; m < 4; ++m)
        #pragma unroll
        for (int n = 0; n < 4; ++n)
            acc[m][n] = (f32x4)0.0f;

    for (int kt = 0; kt < K_DIM / BK; ++kt) {
        const int kofs = kt * BK;

        // Global loads first (overlap with barrier wait).
        f32x4 xa[4];
        i32x4 wv[4];
        #pragma unroll
        for (int q = 0; q < 4; ++q)
            xa[q] = *(const f32x4*)(a_g + (size_t)q * 32 * K_DIM + kofs);
        #pragma unroll
        for (int q = 0; q < 4; ++q)
            wv[q] = *(const i32x4*)(b_g + (size_t)q * 32 * K_DIM + kofs);

        // Convert to bf16: RNE for x (error negligible after scale),
        // exact for weights (|w|<=128 fits bf16's 8 significand bits).
        uint2 ap[4], bp[4];
        #pragma unroll
        for (int q = 0; q < 4; ++q) {
            ap[q] = pack4_bf16(xa[q].x, xa[q].y, xa[q].z, xa[q].w);
            bp[q] = pack4_bf16((float)wv[q].x, (float)wv[q].y,
                               (float)wv[q].z, (float)wv[q].w);
        }

        __syncthreads();   // prev iteration's ds_reads complete before overwrite

        #pragma unroll
        for (int q = 0; q < 4; ++q) {
            *(uint2*)(&As[q * 32 + srow][scol]) = ap[q];
            *(uint2*)(&Bs[q * 32 + srow][scol]) = bp[q];
        }

        __syncthreads();   // tile visible to all waves

        // Fragments (ds_read_b128) + MFMA (m92/m97 verified pattern).
        bf16x8 af[4], bfr[4];
        #pragma unroll
        for (int m = 0; m < 4; ++m)
            af[m] = *(const bf16x8*)(&As[wr * 64 + m * 16 + fr][fq * 8]);
        #pragma unroll
        for (int n = 0; n < 4; ++n)
            bfr[n] = *(const bf16x8*)(&Bs[wc * 64 + n * 16 + fr][fq * 8]);
        #pragma unroll
        for (int m = 0; m < 4; ++m)
            #pragma unroll
            for (int n = 0; n < 4; ++n)
                acc[m][n] = __builtin_amdgcn_mfma_f32_16x16x32_bf16(
                    af[m], bfr[n], acc[m][n], 0, 0, 0);
    }

    // ---- Epilogue: scale + bias, f32 store ----
    // C/D layout (m89-verified): col = lane&15 (=fr), row = (lane>>4)*4 + j.
    const int n_base = tn * BN + wc * 64;
    const int m_base = tm * BM + wr * 64;
    #pragma unroll
    for (int n = 0; n < 4; ++n) {
        const int gn = n_base + n * 16 + fr;
        const float sc = Sc[gn];
        const float bi = Bi[gn];
        #pragma unroll
        for (int m = 0; m < 4; ++m) {
            const int gm0 = m_base + m * 16 + fq * 4;
            #pragma unroll
            for (int j = 0; j < 4; ++j)
                Out[(size_t)(gm0 + j) * N_DIM + gn] = acc[m][n][j] * sc + bi;
        }
    }
}

extern "C" void kernel_launch(void* const* d_in, const int* in_sizes, int n_in,
                              void* d_out, int out_size, void* d_ws, size_t ws_size,
                              hipStream_t stream) {
    const float* X  = (const float*)d_in[0];
    const int*   Wq = (const int*)d_in[1];
    const float* Sc = (const float*)d_in[2];
    const float* Bi = (const float*)d_in[3];
    float*      Out = (float*)d_out;

    dim3 grid((M_DIM / BM) * (N_DIM / BN));   // 64 * 86 = 5504 blocks
    wq8_gemm<<<grid, 256, 0, stream>>>(X, Wq, Sc, Bi, Out);
}

// Round 4
// 997.156 us; speedup vs baseline: 1.3939x; 1.3939x over previous
//
#include <hip/hip_runtime.h>
#include <hip/hip_bf16.h>
#include <stdint.h>

// WeightOnlyInt8Linear: out[m][n] = (sum_k x[m][k]*wq[n][k]) * scale[n] + bias[n]
// M = B*S = 8192, K = 4096, N = 11008.
// Harness dtypes (verified round 3): x f32, wq int32, scale/bias f32, out f32.
//
// Round 4 structure:
//   1) pre-pass kernels: X f32 -> bf16 (RNE), Wq int32 -> bf16 (exact) into d_ws
//      (157.3 MB; falls back to fused round-2 kernel if ws too small)
//   2) pure-bf16 GEMM, m97 ladder structure: 128x128 tile, BK=32, 4 waves,
//      global_load_lds width=16 staging (no VALU staging), 2-barrier K-loop,
//      scale+bias f32 epilogue.

#define M_DIM 8192
#define N_DIM 11008
#define K_DIM 4096
#define BM 128
#define BN 128
#define BK 32

typedef __attribute__((ext_vector_type(4))) float f32x4;
typedef __attribute__((ext_vector_type(8))) short bf16x8;
typedef __attribute__((ext_vector_type(4))) int i32x4;

__device__ __forceinline__ uint2 pack4_bf16(float f0, float f1, float f2, float f3) {
    union { ushort u[4]; uint2 v; } pk;
    pk.u[0] = __bfloat16_as_ushort(__float2bfloat16(f0));
    pk.u[1] = __bfloat16_as_ushort(__float2bfloat16(f1));
    pk.u[2] = __bfloat16_as_ushort(__float2bfloat16(f2));
    pk.u[3] = __bfloat16_as_ushort(__float2bfloat16(f3));
    return pk.v;
}

__device__ __forceinline__ void gload_lds16(const void* g, void* s) {
    __builtin_amdgcn_global_load_lds(
        (const __attribute__((address_space(1))) void*)g,
        (__attribute__((address_space(3))) void*)s, 16, 0, 0);
}

// ---------------- pre-pass: f32 -> bf16 ----------------
extern "C" __global__ __launch_bounds__(256)
void cvt_x_bf16(const float* __restrict__ in, ushort* __restrict__ out, int n8) {
    int idx = blockIdx.x * blockDim.x + threadIdx.x;
    const int stride = gridDim.x * blockDim.x;
    for (; idx < n8; idx += stride) {
        const size_t base = (size_t)idx * 8;
        f32x4 a = *(const f32x4*)(in + base);
        f32x4 b = *(const f32x4*)(in + base + 4);
        uint2 p0 = pack4_bf16(a.x, a.y, a.z, a.w);
        uint2 p1 = pack4_bf16(b.x, b.y, b.z, b.w);
        uint4 o; o.x = p0.x; o.y = p0.y; o.z = p1.x; o.w = p1.y;
        *(uint4*)(out + base) = o;
    }
}

// ---------------- pre-pass: int32 -> bf16 (exact for |v|<=128) ----------------
extern "C" __global__ __launch_bounds__(256)
void cvt_w_bf16(const int* __restrict__ in, ushort* __restrict__ out, int n8) {
    int idx = blockIdx.x * blockDim.x + threadIdx.x;
    const int stride = gridDim.x * blockDim.x;
    for (; idx < n8; idx += stride) {
        const size_t base = (size_t)idx * 8;
        i32x4 a = *(const i32x4*)(in + base);
        i32x4 b = *(const i32x4*)(in + base + 4);
        uint2 p0 = pack4_bf16((float)a.x, (float)a.y, (float)a.z, (float)a.w);
        uint2 p1 = pack4_bf16((float)b.x, (float)b.y, (float)b.z, (float)b.w);
        uint4 o; o.x = p0.x; o.y = p0.y; o.z = p1.x; o.w = p1.y;
        *(uint4*)(out + base) = o;
    }
}

// ---------------- main GEMM: pure bf16, m97 structure ----------------
extern "C" __global__ __launch_bounds__(256)
void wq8_gemm_bf16(const ushort* __restrict__ Xb,   // bf16 bits [M][K]
                   const ushort* __restrict__ Wb,   // bf16 bits [N][K]
                   const float* __restrict__ Sc,
                   const float* __restrict__ Bi,
                   float* __restrict__ Out)
{
    __shared__ __hip_bfloat16 As[BM][BK];   // 8 KB
    __shared__ __hip_bfloat16 Bs[BN][BK];   // 8 KB

    const int tid = threadIdx.x;
    const int w   = tid >> 6;     // wave 0..3
    const int l   = tid & 63;
    const int wr  = w >> 1;       // wave M-half
    const int wc  = w & 1;        // wave N-half
    const int fr  = l & 15;
    const int fq  = l >> 4;

    // XCD swizzle (nwg=5504 divisible by 8) + GROUP_M=8 supertile map.
    const int ntn  = N_DIM / BN;             // 86
    const int nwg  = (M_DIM / BM) * ntn;     // 5504
    const int bid  = (int)blockIdx.x;
    const int wgid = (bid & 7) * (nwg >> 3) + (bid >> 3);
    const int g    = wgid / (8 * ntn);
    const int rr   = wgid % (8 * ntn);
    const int tm   = g * 8 + (rr & 7);
    const int tn   = rr >> 3;

    // Staging: per wave-issue i (0/1), lane l covers
    //   row = w*32 + i*16 + (l>>2), col elems (l&3)*8 (16 B)
    // LDS dest: wave-uniform base (w*2048 + i*1024); HW adds lane*16.
    const ushort* a_g =
        Xb + (size_t)(tm * BM + w * 32 + (l >> 2)) * K_DIM + (l & 3) * 8;
    const ushort* b_g =
        Wb + (size_t)(tn * BN + w * 32 + (l >> 2)) * K_DIM + (l & 3) * 8;
    char* a_s = (char*)(&As[0][0]) + w * 2048;   // wave-uniform
    char* b_s = (char*)(&Bs[0][0]) + w * 2048;

    f32x4 acc[4][4];
    #pragma unroll
    for (int m = 0; m < 4; ++m)
        #pragma unroll
        for (int n = 0; n < 4; ++n)
            acc[m][n] = (f32x4)0.0f;

    for (int kt = 0; kt < K_DIM / BK; ++kt) {
        const int kofs = kt * BK;
        // Async global->LDS staging (4 KB per issue across 4 waves).
        gload_lds16(a_g + kofs,                        a_s);
        gload_lds16(a_g + (size_t)16 * K_DIM + kofs,   a_s + 1024);
        gload_lds16(b_g + kofs,                        b_s);
        gload_lds16(b_g + (size_t)16 * K_DIM + kofs,   b_s + 1024);

        __syncthreads();   // compiler drains vmcnt before barrier -> tile ready

        bf16x8 af[4], bfr[4];
        #pragma unroll
        for (int m = 0; m < 4; ++m)
            af[m] = *(const bf16x8*)(&As[wr * 64 + m * 16 + fr][fq * 8]);
        #pragma unroll
        for (int n = 0; n < 4; ++n)
            bfr[n] = *(const bf16x8*)(&Bs[wc * 64 + n * 16 + fr][fq * 8]);
        #pragma unroll
        for (int m = 0; m < 4; ++m)
            #pragma unroll
            for (int n = 0; n < 4; ++n)
                acc[m][n] = __builtin_amdgcn_mfma_f32_16x16x32_bf16(
                    af[m], bfr[n], acc[m][n], 0, 0, 0);

        __syncthreads();   // all reads done before next overwrite
    }

    // Epilogue: scale + bias, f32 store. C/D: col = fr, row = fq*4 + j.
    const int n_base = tn * BN + wc * 64;
    const int m_base = tm * BM + wr * 64;
    #pragma unroll
    for (int n = 0; n < 4; ++n) {
        const int gn = n_base + n * 16 + fr;
        const float sc = Sc[gn];
        const float bi = Bi[gn];
        #pragma unroll
        for (int m = 0; m < 4; ++m) {
            const int gm0 = m_base + m * 16 + fq * 4;
            #pragma unroll
            for (int j = 0; j < 4; ++j)
                Out[(size_t)(gm0 + j) * N_DIM + gn] = acc[m][n][j] * sc + bi;
        }
    }
}

// ---------------- fallback: fused (round-2, proven) ----------------
extern "C" __global__ __launch_bounds__(256)
void wq8_gemm_fused(const float* __restrict__ X,
                    const int* __restrict__ Wq,
                    const float* __restrict__ Sc,
                    const float* __restrict__ Bi,
                    float* __restrict__ Out)
{
    __shared__ __hip_bfloat16 As[BM][BK];
    __shared__ __hip_bfloat16 Bs[BN][BK];

    const int tid = threadIdx.x;
    const int w   = tid >> 6;
    const int l   = tid & 63;
    const int wr  = w >> 1;
    const int wc  = w & 1;
    const int fr  = l & 15;
    const int fq  = l >> 4;

    const int ntn  = N_DIM / BN;
    const int nwg  = (M_DIM / BM) * ntn;
    const int bid  = (int)blockIdx.x;
    const int wgid = (bid & 7) * (nwg >> 3) + (bid >> 3);
    const int g    = wgid / (8 * ntn);
    const int rr   = wgid % (8 * ntn);
    const int tm   = g * 8 + (rr & 7);
    const int tn   = rr >> 3;

    const int srow = tid >> 3;
    const int scol = (tid & 7) * 4;
    const float* a_g = X  + (size_t)(tm * BM + srow) * K_DIM + scol;
    const int*   b_g = Wq + (size_t)(tn * BN + srow) * K_DIM + scol;

    f32x4 acc[4][4];
    #pragma unroll
    for (int m = 0; m < 4; ++m)
        #pragma unroll
        for (int n = 0; n < 4; ++n)
            acc[m][n] = (f32x4)0.0f;

    for (int kt = 0; kt < K_DIM / BK; ++kt) {
        const int kofs = kt * BK;
        f32x4 xa[4];
        i32x4 wv[4];
        #pragma unroll
        for (int q = 0; q < 4; ++q)
            xa[q] = *(const f32x4*)(a_g + (size_t)q * 32 * K_DIM + kofs);
        #pragma unroll
        for (int q = 0; q < 4; ++q)
            wv[q] = *(const i32x4*)(b_g + (size_t)q * 32 * K_DIM + kofs);

        uint2 ap[4], bp[4];
        #pragma unroll
        for (int q = 0; q < 4; ++q) {
            ap[q] = pack4_bf16(xa[q].x, xa[q].y, xa[q].z, xa[q].w);
            bp[q] = pack4_bf16((float)wv[q].x, (float)wv[q].y,
                               (float)wv[q].z, (float)wv[q].w);
        }

        __syncthreads();
        #pragma unroll
        for (int q = 0; q < 4; ++q) {
            *(uint2*)(&As[q * 32 + srow][scol]) = ap[q];
            *(uint2*)(&Bs[q * 32 + srow][scol]) = bp[q];
        }
        __syncthreads();

        bf16x8 af[4], bfr[4];
        #pragma unroll
        for (int m = 0; m < 4; ++m)
            af[m] = *(const bf16x8*)(&As[wr * 64 + m * 16 + fr][fq * 8]);
        #pragma unroll
        for (int n = 0; n < 4; ++n)
            bfr[n] = *(const bf16x8*)(&Bs[wc * 64 + n * 16 + fr][fq * 8]);
        #pragma unroll
        for (int m = 0; m < 4; ++m)
            #pragma unroll
            for (int n = 0; n < 4; ++n)
                acc[m][n] = __builtin_amdgcn_mfma_f32_16x16x32_bf16(
                    af[m], bfr[n], acc[m][n], 0, 0, 0);
    }

    const int n_base = tn * BN + wc * 64;
    const int m_base = tm * BM + wr * 64;
    #pragma unroll
    for (int n = 0; n < 4; ++n) {
        const int gn = n_base + n * 16 + fr;
        const float sc = Sc[gn];
        const float bi = Bi[gn];
        #pragma unroll
        for (int m = 0; m < 4; ++m) {
            const int gm0 = m_base + m * 16 + fq * 4;
            #pragma unroll
            for (int j = 0; j < 4; ++j)
                Out[(size_t)(gm0 + j) * N_DIM + gn] = acc[m][n][j] * sc + bi;
        }
    }
}

extern "C" void kernel_launch(void* const* d_in, const int* in_sizes, int n_in,
                              void* d_out, int out_size, void* d_ws, size_t ws_size,
                              hipStream_t stream) {
    const float* X  = (const float*)d_in[0];
    const int*   Wq = (const int*)d_in[1];
    const float* Sc = (const float*)d_in[2];
    const float* Bi = (const float*)d_in[3];
    float*      Out = (float*)d_out;

    const size_t nX = (size_t)M_DIM * K_DIM;          // 33,554,432
    const size_t nW = (size_t)N_DIM * K_DIM;          // 45,088,768
    const size_t ws_needed = (nX + nW) * sizeof(ushort);   // 157,286,400 B

    dim3 grid((M_DIM / BM) * (N_DIM / BN));   // 5504 blocks

    if (ws_size >= ws_needed) {
        ushort* Xb = (ushort*)d_ws;
        ushort* Wb = Xb + nX;
        cvt_x_bf16<<<2048, 256, 0, stream>>>(X, Xb, (int)(nX / 8));
        cvt_w_bf16<<<2048, 256, 0, stream>>>(Wq, Wb, (int)(nW / 8));
        wq8_gemm_bf16<<<grid, 256, 0, stream>>>(Xb, Wb, Sc, Bi, Out);
    } else {
        wq8_gemm_fused<<<grid, 256, 0, stream>>>(X, Wq, Sc, Bi, Out);
    }
}

// Round 5
// 766.314 us; speedup vs baseline: 1.8138x; 1.3012x over previous
//
#include <hip/hip_runtime.h>
#include <hip/hip_bf16.h>
#include <stdint.h>

// WeightOnlyInt8Linear: out[m][n] = (sum_k x[m][k]*wq[n][k]) * scale[n] + bias[n]
// M = B*S = 8192, K = 4096, N = 11008.
// Harness dtypes (verified round 3): x f32, wq int32, scale/bias f32, out f32.
//
// Round 5:
//   1) pre-pass: X f32->bf16 (RNE), Wq int32->bf16 (exact) into d_ws.
//   2) 256x256 8-phase GEMM (m201-style): BK=64, 8 waves (2Mx4N), 128KB LDS
//      double-buffer, global_load_lds w/ inverse-swizzled source + XOR-swizzled
//      ds_read (T2), per-phase barrier+MFMA clusters w/ setprio (T3+T5),
//      counted vmcnt(6)/vmcnt(8) — never drain-0 in steady state (T4).
//
// Schedule correctness (region-death argument):
//   Phases per K-tile t (buf = t&1): ph0=(m-half0 x n-half0), ph1=(m0,n1),
//   ph2=(m1,n0), ph3=(m1,n1). A-frags read once per m-half (ph0/ph2, cached
//   in VGPR for the following phase); B-frags read once per n-half (ph0/ph1,
//   cached for ph2/ph3). Hence region last-read phases: A-m0: ph0, B-n0: ph0,
//   B-n1: ph1, A-m1: ph2.
//   Staging (2 x global_load_lds each): ph0: A-m1(t+1)->nbuf (prev contents
//   tile t-1's A-m1, dead after t-1.ph2's lgkm0+barrier); ph1: B-n1(t+1)->nbuf
//   (dead after t-1.ph1); ph2: A-m0(t+2)->buf (tile t's A-m0 dead after ph0);
//   ph3: B-n0(t+2)->buf (dead after ph0).
//   Waits: end-ph3 vmcnt(8) guarantees A-m0(t+1),B-n0(t+1) (4 younger
//   half-tiles = 8 loads outstanding allowed); end-ph0 vmcnt(6) guarantees
//   B-n1(t) and A-m1(t) (3 younger half-tiles). Tail tightens counts.
//   Cross-wave visibility: each vmcnt precedes a barrier that precedes the
//   dependent ds_reads.

#define M_DIM 8192
#define N_DIM 11008
#define K_DIM 4096

// 128x128 fused fallback geometry (only used if ws too small)
#define BM 128
#define BN 128
#define BK 32

// 256x256 8-phase geometry
#define BM2 256
#define BN2 256
#define BK2 64
#define NT2 (K_DIM / BK2)   // 64

typedef __attribute__((ext_vector_type(4))) float f32x4;
typedef __attribute__((ext_vector_type(8))) short bf16x8;
typedef __attribute__((ext_vector_type(4))) int i32x4;

__device__ __forceinline__ uint2 pack4_bf16(float f0, float f1, float f2, float f3) {
    union { ushort u[4]; uint2 v; } pk;
    pk.u[0] = __bfloat16_as_ushort(__float2bfloat16(f0));
    pk.u[1] = __bfloat16_as_ushort(__float2bfloat16(f1));
    pk.u[2] = __bfloat16_as_ushort(__float2bfloat16(f2));
    pk.u[3] = __bfloat16_as_ushort(__float2bfloat16(f3));
    return pk.v;
}

__device__ __forceinline__ void gload_lds16(const void* g, void* s) {
    __builtin_amdgcn_global_load_lds(
        (const __attribute__((address_space(1))) void*)g,
        (__attribute__((address_space(3))) void*)s, 16, 0, 0);
}

#define S_BARRIER() __builtin_amdgcn_s_barrier()
#define SCHED0()    __builtin_amdgcn_sched_barrier(0)
#define LGKM0() do { asm volatile("s_waitcnt lgkmcnt(0)" ::: "memory"); \
                     __builtin_amdgcn_sched_barrier(0); } while (0)
#define VMC(N)  do { asm volatile("s_waitcnt vmcnt(" #N ")" ::: "memory"); } while (0)

#define RD16(OFF) (*(const bf16x8*)(lds + (OFF)))

// 16-MFMA quadrant cluster, setprio-wrapped (T5). MH/NH must be literals.
#define QUAD(MH, NH, A, B)                                                     \
  do {                                                                         \
    __builtin_amdgcn_s_setprio(1);                                             \
    _Pragma("unroll")                                                          \
    for (int mi = 0; mi < 4; ++mi) {                                           \
      _Pragma("unroll")                                                        \
      for (int ni = 0; ni < 2; ++ni) {                                         \
        acc[(MH)*4+mi][(NH)*2+ni] = __builtin_amdgcn_mfma_f32_16x16x32_bf16(   \
            (A)[mi][0], (B)[ni][0], acc[(MH)*4+mi][(NH)*2+ni], 0, 0, 0);       \
        acc[(MH)*4+mi][(NH)*2+ni] = __builtin_amdgcn_mfma_f32_16x16x32_bf16(   \
            (A)[mi][1], (B)[ni][1], acc[(MH)*4+mi][(NH)*2+ni], 0, 0, 0);       \
      }                                                                        \
    }                                                                          \
    __builtin_amdgcn_s_setprio(0);                                             \
  } while (0)

// ---------------- pre-pass: f32 -> bf16 ----------------
extern "C" __global__ __launch_bounds__(256)
void cvt_x_bf16(const float* __restrict__ in, ushort* __restrict__ out, int n8) {
    int idx = blockIdx.x * blockDim.x + threadIdx.x;
    const int stride = gridDim.x * blockDim.x;
    for (; idx < n8; idx += stride) {
        const size_t base = (size_t)idx * 8;
        f32x4 a = *(const f32x4*)(in + base);
        f32x4 b = *(const f32x4*)(in + base + 4);
        uint2 p0 = pack4_bf16(a.x, a.y, a.z, a.w);
        uint2 p1 = pack4_bf16(b.x, b.y, b.z, b.w);
        uint4 o; o.x = p0.x; o.y = p0.y; o.z = p1.x; o.w = p1.y;
        *(uint4*)(out + base) = o;
    }
}

// ---------------- pre-pass: int32 -> bf16 (exact for |v|<=128) ----------------
extern "C" __global__ __launch_bounds__(256)
void cvt_w_bf16(const int* __restrict__ in, ushort* __restrict__ out, int n8) {
    int idx = blockIdx.x * blockDim.x + threadIdx.x;
    const int stride = gridDim.x * blockDim.x;
    for (; idx < n8; idx += stride) {
        const size_t base = (size_t)idx * 8;
        i32x4 a = *(const i32x4*)(in + base);
        i32x4 b = *(const i32x4*)(in + base + 4);
        uint2 p0 = pack4_bf16((float)a.x, (float)a.y, (float)a.z, (float)a.w);
        uint2 p1 = pack4_bf16((float)b.x, (float)b.y, (float)b.z, (float)b.w);
        uint4 o; o.x = p0.x; o.y = p0.y; o.z = p1.x; o.w = p1.y;
        *(uint4*)(out + base) = o;
    }
}

// ---------------- main GEMM: 256x256, 8-wave, 8-phase ----------------
extern "C" __global__ __launch_bounds__(512, 2)
void wq8_gemm_256(const ushort* __restrict__ Xb,   // bf16 bits [M][K]
                  const ushort* __restrict__ Wb,   // bf16 bits [N][K]
                  const float* __restrict__ Sc,
                  const float* __restrict__ Bi,
                  float* __restrict__ Out)
{
    // LDS: buf b at b*65536; within buf: A[256][64]bf16 at 0, B[256][64] at 32768.
    __shared__ __align__(16) char lds[131072];

    const int tid = (int)threadIdx.x;
    const int l   = tid & 63;
    const int w   = tid >> 6;      // wave 0..7
    const int wr  = w >> 2;        // 0..1  (M-half of output tile)
    const int wc  = w & 3;         // 0..3  (N-quarter)
    const int fr  = l & 15;
    const int fq  = l >> 4;

    // XCD swizzle (nwg = 1376 = 8*172) + GROUP_M=8 supertile map.
    const int nwg  = (M_DIM / BM2) * (N_DIM / BN2);   // 32*43 = 1376
    const int bid  = (int)blockIdx.x;
    const int wgid = (bid & 7) * (nwg >> 3) + (bid >> 3);
    const int grp  = wgid / 344;          // 8 * 43
    const int rr   = wgid % 344;
    const int tm   = grp * 8 + (rr & 7);  // 0..31
    const int tn   = rr >> 3;             // 0..42
    const int gM   = tm * BM2;
    const int gN   = tn * BN2;

    // Staging: each global_load_lds covers 8 rows x 64 bf16 per wave (1KB).
    // LDS content is written LINEARLY; the XOR swizzle is realized by
    // inverse-permuting the per-lane GLOBAL source column (rule 21 / m173):
    // LDS slot s of row r holds logical col-slot s ^ (r&7).
    const int slotOfs = ((l & 7) ^ (l >> 3)) * 8;    // source col offset (elems)

    // Reader: frag(row r, kk) at byte r*128 + ((kk*64 + (l>>4)*16) ^ ((r&7)<<4));
    // r&7 == l&7 for all our frag rows (row bases are multiples of 16).
    const int cA0  = ((l >> 4) * 16) ^ ((l & 7) << 4);
    const int cA1  = cA0 ^ 64;
    const int arow = wr * 16384 + (l & 15) * 128;          // + m*2048 + cA{kk}
    const int brow = 32768 + (wc * 64 + (l & 15)) * 128;   // + n*2048 + cA{kk}

    // A half-tile stage: rows [rowbase, rowbase+64) of the LDS A tile.
    auto STAGE_A = [&](int bufb, int rowbase, int kofs) {
        const ushort* src = Xb + (size_t)(gM + rowbase + (tid >> 3)) * K_DIM
                               + kofs + slotOfs;
        char* dst = lds + bufb + rowbase * 128 + (w << 10);   // wave-uniform
        gload_lds16(src, dst);
    };
    // B n-half stage: 16 chunks of 8 rows; wave w takes chunks w and 8+w.
    // h=0 -> rows [q*64, q*64+32) (n in {0,1}); h=1 -> +32 (n in {2,3}).
    auto STAGE_B = [&](int bufb, int j, int h, int kofs) {
        const int c = j * 8 + w;
        const int rowbase = (c >> 2) * 64 + h * 32 + (c & 3) * 8;
        const ushort* src = Wb + (size_t)(gN + rowbase + (l >> 3)) * K_DIM
                               + kofs + slotOfs;
        char* dst = lds + bufb + 32768 + rowbase * 128;       // wave-uniform
        gload_lds16(src, dst);
    };

    f32x4 acc[8][4];
    #pragma unroll
    for (int m = 0; m < 8; ++m)
        #pragma unroll
        for (int n = 0; n < 4; ++n)
            acc[m][n] = (f32x4)0.0f;

    // Prologue: tile0 complete + tile1 {A-m0, B-n0}  (12 loads; canonical order).
    STAGE_A(0, 0, 0);        STAGE_A(0, 128, 0);        // A-m0(0)
    STAGE_B(0, 0, 0, 0);     STAGE_B(0, 1, 0, 0);       // B-n0(0)
    STAGE_A(0, 64, 0);       STAGE_A(0, 192, 0);        // A-m1(0)
    STAGE_B(0, 0, 1, 0);     STAGE_B(0, 1, 1, 0);       // B-n1(0)
    STAGE_A(65536, 0, BK2);  STAGE_A(65536, 128, BK2);  // A-m0(1)
    STAGE_B(65536, 0, 0, BK2); STAGE_B(65536, 1, 0, BK2); // B-n0(1)
    VMC(8);                 // tile0's A-m0,B-n0 landed (8 younger allowed)
    S_BARRIER(); SCHED0();

    bf16x8 af[4][2], bf01[2][2], bf23[2][2];

    for (int t = 0; t < NT2; ++t) {
        const int buf  = (t & 1) << 16;
        const int nbuf = buf ^ 65536;
        const int k1   = (t + 1) * BK2;
        const int k2   = (t + 2) * BK2;

        // ---------- phase 0: C(m0,n0); stage A-m1(t+1) ----------
        #pragma unroll
        for (int mi = 0; mi < 4; ++mi) {
            af[mi][0] = RD16(buf + arow + mi * 2048 + cA0);
            af[mi][1] = RD16(buf + arow + mi * 2048 + cA1);
        }
        #pragma unroll
        for (int ni = 0; ni < 2; ++ni) {
            bf01[ni][0] = RD16(buf + brow + ni * 2048 + cA0);
            bf01[ni][1] = RD16(buf + brow + ni * 2048 + cA1);
        }
        if (t + 1 < NT2) { STAGE_A(nbuf, 64, k1); STAGE_A(nbuf, 192, k1); }
        S_BARRIER();
        LGKM0();
        QUAD(0, 0, af, bf01);
        if (t + 1 < NT2) { VMC(6); } else { VMC(0); }
        S_BARRIER(); SCHED0();

        // ---------- phase 1: C(m0,n1); stage B-n1(t+1) ----------
        #pragma unroll
        for (int ni = 0; ni < 2; ++ni) {
            bf23[ni][0] = RD16(buf + brow + (2 + ni) * 2048 + cA0);
            bf23[ni][1] = RD16(buf + brow + (2 + ni) * 2048 + cA1);
        }
        if (t + 1 < NT2) { STAGE_B(nbuf, 0, 1, k1); STAGE_B(nbuf, 1, 1, k1); }
        S_BARRIER();
        LGKM0();
        QUAD(0, 1, af, bf23);
        S_BARRIER(); SCHED0();

        // ---------- phase 2: C(m1,n0); stage A-m0(t+2) ----------
        #pragma unroll
        for (int mi = 0; mi < 4; ++mi) {
            af[mi][0] = RD16(buf + arow + 8192 + mi * 2048 + cA0);
            af[mi][1] = RD16(buf + arow + 8192 + mi * 2048 + cA1);
        }
        if (t + 2 < NT2) { STAGE_A(buf, 0, k2); STAGE_A(buf, 128, k2); }
        S_BARRIER();
        LGKM0();
        QUAD(1, 0, af, bf01);
        S_BARRIER(); SCHED0();

        // ---------- phase 3: C(m1,n1); stage B-n0(t+2) ----------
        if (t + 2 < NT2) { STAGE_B(buf, 0, 0, k2); STAGE_B(buf, 1, 0, k2); }
        S_BARRIER();
        LGKM0();
        QUAD(1, 1, af, bf23);
        if (t + 2 < NT2)      { VMC(8); }
        else if (t + 1 < NT2) { VMC(4); }
        S_BARRIER(); SCHED0();
    }

    // ---- Epilogue: scale + bias, f32 store. C/D: col=fr, row=fq*4+j. ----
    const int gnBase = gN + wc * 64;
    const int gmBase = gM + wr * 128;
    #pragma unroll
    for (int n = 0; n < 4; ++n) {
        const int gn = gnBase + n * 16 + fr;
        const float sc = Sc[gn];
        const float bi = Bi[gn];
        #pragma unroll
        for (int m = 0; m < 8; ++m) {
            const int gm0 = gmBase + m * 16 + fq * 4;
            #pragma unroll
            for (int j = 0; j < 4; ++j)
                Out[(size_t)(gm0 + j) * N_DIM + gn] = acc[m][n][j] * sc + bi;
        }
    }
}

// ---------------- fallback: fused 128x128 (round-2, proven) ----------------
extern "C" __global__ __launch_bounds__(256)
void wq8_gemm_fused(const float* __restrict__ X,
                    const int* __restrict__ Wq,
                    const float* __restrict__ Sc,
                    const float* __restrict__ Bi,
                    float* __restrict__ Out)
{
    __shared__ __hip_bfloat16 As[BM][BK];
    __shared__ __hip_bfloat16 Bs[BN][BK];

    const int tid = threadIdx.x;
    const int w   = tid >> 6;
    const int l   = tid & 63;
    const int wr  = w >> 1;
    const int wc  = w & 1;
    const int fr  = l & 15;
    const int fq  = l >> 4;

    const int ntn  = N_DIM / BN;
    const int nwg  = (M_DIM / BM) * ntn;
    const int bid  = (int)blockIdx.x;
    const int wgid = (bid & 7) * (nwg >> 3) + (bid >> 3);
    const int g    = wgid / (8 * ntn);
    const int rr   = wgid % (8 * ntn);
    const int tm   = g * 8 + (rr & 7);
    const int tn   = rr >> 3;

    const int srow = tid >> 3;
    const int scol = (tid & 7) * 4;
    const float* a_g = X  + (size_t)(tm * BM + srow) * K_DIM + scol;
    const int*   b_g = Wq + (size_t)(tn * BN + srow) * K_DIM + scol;

    f32x4 acc[4][4];
    #pragma unroll
    for (int m = 0; m < 4; ++m)
        #pragma unroll
        for (int n = 0; n < 4; ++n)
            acc[m][n] = (f32x4)0.0f;

    for (int kt = 0; kt < K_DIM / BK; ++kt) {
        const int kofs = kt * BK;
        f32x4 xa[4];
        i32x4 wv[4];
        #pragma unroll
        for (int q = 0; q < 4; ++q)
            xa[q] = *(const f32x4*)(a_g + (size_t)q * 32 * K_DIM + kofs);
        #pragma unroll
        for (int q = 0; q < 4; ++q)
            wv[q] = *(const i32x4*)(b_g + (size_t)q * 32 * K_DIM + kofs);

        uint2 ap[4], bp[4];
        #pragma unroll
        for (int q = 0; q < 4; ++q) {
            ap[q] = pack4_bf16(xa[q].x, xa[q].y, xa[q].z, xa[q].w);
            bp[q] = pack4_bf16((float)wv[q].x, (float)wv[q].y,
                               (float)wv[q].z, (float)wv[q].w);
        }

        __syncthreads();
        #pragma unroll
        for (int q = 0; q < 4; ++q) {
            *(uint2*)(&As[q * 32 + srow][scol]) = ap[q];
            *(uint2*)(&Bs[q * 32 + srow][scol]) = bp[q];
        }
        __syncthreads();

        bf16x8 af[4], bfr[4];
        #pragma unroll
        for (int m = 0; m < 4; ++m)
            af[m] = *(const bf16x8*)(&As[wr * 64 + m * 16 + fr][fq * 8]);
        #pragma unroll
        for (int n = 0; n < 4; ++n)
            bfr[n] = *(const bf16x8*)(&Bs[wc * 64 + n * 16 + fr][fq * 8]);
        #pragma unroll
        for (int m = 0; m < 4; ++m)
            #pragma unroll
            for (int n = 0; n < 4; ++n)
                acc[m][n] = __builtin_amdgcn_mfma_f32_16x16x32_bf16(
                    af[m], bfr[n], acc[m][n], 0, 0, 0);
    }

    const int n_base = tn * BN + wc * 64;
    const int m_base = tm * BM + wr * 64;
    #pragma unroll
    for (int n = 0; n < 4; ++n) {
        const int gn = n_base + n * 16 + fr;
        const float sc = Sc[gn];
        const float bi = Bi[gn];
        #pragma unroll
        for (int m = 0; m < 4; ++m) {
            const int gm0 = m_base + m * 16 + fq * 4;
            #pragma unroll
            for (int j = 0; j < 4; ++j)
                Out[(size_t)(gm0 + j) * N_DIM + gn] = acc[m][n][j] * sc + bi;
        }
    }
}

extern "C" void kernel_launch(void* const* d_in, const int* in_sizes, int n_in,
                              void* d_out, int out_size, void* d_ws, size_t ws_size,
                              hipStream_t stream) {
    const float* X  = (const float*)d_in[0];
    const int*   Wq = (const int*)d_in[1];
    const float* Sc = (const float*)d_in[2];
    const float* Bi = (const float*)d_in[3];
    float*      Out = (float*)d_out;

    const size_t nX = (size_t)M_DIM * K_DIM;
    const size_t nW = (size_t)N_DIM * K_DIM;
    const size_t ws_needed = (nX + nW) * sizeof(ushort);   // 157.3 MB

    if (ws_size >= ws_needed) {
        ushort* Xb = (ushort*)d_ws;
        ushort* Wb = Xb + nX;
        cvt_x_bf16<<<2048, 256, 0, stream>>>(X, Xb, (int)(nX / 8));
        cvt_w_bf16<<<2048, 256, 0, stream>>>(Wq, Wb, (int)(nW / 8));
        dim3 grid2((M_DIM / BM2) * (N_DIM / BN2));   // 32*43 = 1376
        wq8_gemm_256<<<grid2, 512, 0, stream>>>(Xb, Wb, Sc, Bi, Out);
    } else {
        dim3 grid((M_DIM / BM) * (N_DIM / BN));      // 5504
        wq8_gemm_fused<<<grid, 256, 0, stream>>>(X, Wq, Sc, Bi, Out);
    }
}

// Round 6
// 764.018 us; speedup vs baseline: 1.8193x; 1.0030x over previous
//
#include <hip/hip_runtime.h>
#include <hip/hip_bf16.h>
#include <stdint.h>

// WeightOnlyInt8Linear: out[m][n] = (sum_k x[m][k]*wq[n][k]) * scale[n] + bias[n]
// M = B*S = 8192, K = 4096, N = 11008.
// Harness dtypes (verified round 3): x f32, wq int32, scale/bias f32, out f32.
//
// Round 6: R5's 256x256 8-phase schedule + one-phase ds_read software pipeline
// ("late reads"): each QUAD's LDS fragments are read in the PREVIOUS phase
// (pinned after that phase's QUAD via sched_barrier(0)), and explicit
// lgkmcnt(0) drains are removed — the compiler emits counted lgkm waits at
// first use, so read-drain overlaps barriers/MFMA instead of serializing.
//
// Visibility/wait derivation (steady state, stages 2 loads each):
//   issue order: ... ph2(t-1):A-m0(t+1), ph3(t-1):B-n0(t+1), ph0(t):A-m1(t+1),
//                ph1(t):B-n1(t+1), ph2(t):A-m0(t+2), ph3(t):B-n0(t+2) ...
//   VMC(6)@end-ph0(t): leaves {A-m0(t+1),B-n0(t+1),A-m1(t+1)} -> guarantees
//     A-m1(t),B-n1(t) landed => ph1(t) may read B23(t), late-read A1(t).
//   VMC(4)@end-ph1(t): leaves {A-m1(t+1),B-n1(t+1)} -> guarantees
//     A-m0(t+1),B-n0(t+1) => late reads of B01(t+1)@ph2, A0(t+1)@ph3.
//   Stage-overwrite safety: every staged region's previous contents were last
//   READ >=1 phase earlier and consumed by a QUAD before an intervening
//   barrier (compiler lgkm wait before first use), so all waves' reads are
//   complete before any wave issues the overwriting gload_lds.
//   Tail: t=63 uses VMC(0)@end-ph0; late next-tile reads guarded t+1<NT2.

#define M_DIM 8192
#define N_DIM 11008
#define K_DIM 4096

// 128x128 fused fallback geometry (only used if ws too small)
#define BM 128
#define BN 128
#define BK 32

// 256x256 8-phase geometry
#define BM2 256
#define BN2 256
#define BK2 64
#define NT2 (K_DIM / BK2)   // 64

typedef __attribute__((ext_vector_type(4))) float f32x4;
typedef __attribute__((ext_vector_type(8))) short bf16x8;
typedef __attribute__((ext_vector_type(4))) int i32x4;

__device__ __forceinline__ uint2 pack4_bf16(float f0, float f1, float f2, float f3) {
    union { ushort u[4]; uint2 v; } pk;
    pk.u[0] = __bfloat16_as_ushort(__float2bfloat16(f0));
    pk.u[1] = __bfloat16_as_ushort(__float2bfloat16(f1));
    pk.u[2] = __bfloat16_as_ushort(__float2bfloat16(f2));
    pk.u[3] = __bfloat16_as_ushort(__float2bfloat16(f3));
    return pk.v;
}

__device__ __forceinline__ void gload_lds16(const void* g, void* s) {
    __builtin_amdgcn_global_load_lds(
        (const __attribute__((address_space(1))) void*)g,
        (__attribute__((address_space(3))) void*)s, 16, 0, 0);
}

#define SCHED0()  __builtin_amdgcn_sched_barrier(0)
// barrier + compiler memory fence (reads must not hoist above the barrier)
#define BAR() do { __builtin_amdgcn_s_barrier(); \
                   asm volatile("" ::: "memory"); } while (0)
#define VMC(N)  do { asm volatile("s_waitcnt vmcnt(" #N ")" ::: "memory"); } while (0)

#define RD16(OFF) (*(const bf16x8*)(lds + (OFF)))

// 16-MFMA quadrant cluster, setprio-wrapped (T5). MH/NH must be literals.
#define QUAD(MH, NH, A, B)                                                     \
  do {                                                                         \
    __builtin_amdgcn_s_setprio(1);                                             \
    _Pragma("unroll")                                                          \
    for (int mi = 0; mi < 4; ++mi) {                                           \
      _Pragma("unroll")                                                        \
      for (int ni = 0; ni < 2; ++ni) {                                         \
        acc[(MH)*4+mi][(NH)*2+ni] = __builtin_amdgcn_mfma_f32_16x16x32_bf16(   \
            (A)[mi][0], (B)[ni][0], acc[(MH)*4+mi][(NH)*2+ni], 0, 0, 0);       \
        acc[(MH)*4+mi][(NH)*2+ni] = __builtin_amdgcn_mfma_f32_16x16x32_bf16(   \
            (A)[mi][1], (B)[ni][1], acc[(MH)*4+mi][(NH)*2+ni], 0, 0, 0);       \
      }                                                                        \
    }                                                                          \
    __builtin_amdgcn_s_setprio(0);                                             \
  } while (0)

// ---------------- pre-pass: f32 -> bf16 ----------------
extern "C" __global__ __launch_bounds__(256)
void cvt_x_bf16(const float* __restrict__ in, ushort* __restrict__ out, int n8) {
    int idx = blockIdx.x * blockDim.x + threadIdx.x;
    const int stride = gridDim.x * blockDim.x;
    for (; idx < n8; idx += stride) {
        const size_t base = (size_t)idx * 8;
        f32x4 a = *(const f32x4*)(in + base);
        f32x4 b = *(const f32x4*)(in + base + 4);
        uint2 p0 = pack4_bf16(a.x, a.y, a.z, a.w);
        uint2 p1 = pack4_bf16(b.x, b.y, b.z, b.w);
        uint4 o; o.x = p0.x; o.y = p0.y; o.z = p1.x; o.w = p1.y;
        *(uint4*)(out + base) = o;
    }
}

// ---------------- pre-pass: int32 -> bf16 (exact for |v|<=128) ----------------
extern "C" __global__ __launch_bounds__(256)
void cvt_w_bf16(const int* __restrict__ in, ushort* __restrict__ out, int n8) {
    int idx = blockIdx.x * blockDim.x + threadIdx.x;
    const int stride = gridDim.x * blockDim.x;
    for (; idx < n8; idx += stride) {
        const size_t base = (size_t)idx * 8;
        i32x4 a = *(const i32x4*)(in + base);
        i32x4 b = *(const i32x4*)(in + base + 4);
        uint2 p0 = pack4_bf16((float)a.x, (float)a.y, (float)a.z, (float)a.w);
        uint2 p1 = pack4_bf16((float)b.x, (float)b.y, (float)b.z, (float)b.w);
        uint4 o; o.x = p0.x; o.y = p0.y; o.z = p1.x; o.w = p1.y;
        *(uint4*)(out + base) = o;
    }
}

// ---------------- main GEMM: 256x256, 8-wave, 8-phase, late-read pipeline ----
extern "C" __global__ __launch_bounds__(512, 2)
void wq8_gemm_256(const ushort* __restrict__ Xb,   // bf16 bits [M][K]
                  const ushort* __restrict__ Wb,   // bf16 bits [N][K]
                  const float* __restrict__ Sc,
                  const float* __restrict__ Bi,
                  float* __restrict__ Out)
{
    // LDS: buf b at b*65536; within buf: A[256][64]bf16 at 0, B[256][64] at 32768.
    __shared__ __align__(16) char lds[131072];

    const int tid = (int)threadIdx.x;
    const int l   = tid & 63;
    const int w   = tid >> 6;      // wave 0..7
    const int wr  = w >> 2;        // 0..1  (M-half of output tile)
    const int wc  = w & 3;         // 0..3  (N-quarter)
    const int fr  = l & 15;
    const int fq  = l >> 4;

    // XCD swizzle (nwg = 1376 = 8*172) + GROUP_M=8 supertile map.
    const int nwg  = (M_DIM / BM2) * (N_DIM / BN2);   // 32*43 = 1376
    const int bid  = (int)blockIdx.x;
    const int wgid = (bid & 7) * (nwg >> 3) + (bid >> 3);
    const int grp  = wgid / 344;          // 8 * 43
    const int rr   = wgid % 344;
    const int tm   = grp * 8 + (rr & 7);  // 0..31
    const int tn   = rr >> 3;             // 0..42
    const int gM   = tm * BM2;
    const int gN   = tn * BN2;

    // Staging: LDS written LINEARLY by gload_lds; XOR swizzle realized by
    // inverse-permuting the per-lane GLOBAL source column (rule 21 / m173).
    const int slotOfs = ((l & 7) ^ (l >> 3)) * 8;    // source col offset (elems)

    // Reader: frag(row r, kk) at byte r*128 + ((kk*64 + (l>>4)*16) ^ ((r&7)<<4))
    const int cA0  = ((l >> 4) * 16) ^ ((l & 7) << 4);
    const int cA1  = cA0 ^ 64;
    const int arow = wr * 16384 + (l & 15) * 128;          // + mi*2048 (+8192 for m1)
    const int brow = 32768 + (wc * 64 + (l & 15)) * 128;   // + ni*2048

    auto STAGE_A = [&](int bufb, int rowbase, int kofs) {
        const ushort* src = Xb + (size_t)(gM + rowbase + (tid >> 3)) * K_DIM
                               + kofs + slotOfs;
        char* dst = lds + bufb + rowbase * 128 + (w << 10);   // wave-uniform
        gload_lds16(src, dst);
    };
    auto STAGE_B = [&](int bufb, int j, int h, int kofs) {
        const int c = j * 8 + w;
        const int rowbase = (c >> 2) * 64 + h * 32 + (c & 3) * 8;
        const ushort* src = Wb + (size_t)(gN + rowbase + (l >> 3)) * K_DIM
                               + kofs + slotOfs;
        char* dst = lds + bufb + 32768 + rowbase * 128;       // wave-uniform
        gload_lds16(src, dst);
    };

    f32x4 acc[8][4];
    #pragma unroll
    for (int m = 0; m < 8; ++m)
        #pragma unroll
        for (int n = 0; n < 4; ++n)
            acc[m][n] = (f32x4)0.0f;

    // Prologue: tile0 complete + tile1 {A-m0, B-n0} (12 loads, canonical order).
    STAGE_A(0, 0, 0);        STAGE_A(0, 128, 0);        // A-m0(0)
    STAGE_B(0, 0, 0, 0);     STAGE_B(0, 1, 0, 0);       // B-n0(0)
    STAGE_A(0, 64, 0);       STAGE_A(0, 192, 0);        // A-m1(0)
    STAGE_B(0, 0, 1, 0);     STAGE_B(0, 1, 1, 0);       // B-n1(0)
    STAGE_A(65536, 0, BK2);  STAGE_A(65536, 128, BK2);  // A-m0(1)
    STAGE_B(65536, 0, 0, BK2); STAGE_B(65536, 1, 0, BK2); // B-n0(1)
    VMC(8);                 // tile0's A-m0,B-n0 landed
    BAR(); SCHED0();

    bf16x8 af[4][2], bf01[2][2], bf23[2][2];

    // Prologue reads: A0(0), B01(0)  (consumed by QUAD(0,0) at t=0).
    #pragma unroll
    for (int mi = 0; mi < 4; ++mi) {
        af[mi][0] = RD16(arow + mi * 2048 + cA0);
        af[mi][1] = RD16(arow + mi * 2048 + cA1);
    }
    #pragma unroll
    for (int ni = 0; ni < 2; ++ni) {
        bf01[ni][0] = RD16(brow + ni * 2048 + cA0);
        bf01[ni][1] = RD16(brow + ni * 2048 + cA1);
    }

    for (int t = 0; t < NT2; ++t) {
        const int buf  = (t & 1) << 16;
        const int nbuf = buf ^ 65536;
        const int k1   = (t + 1) * BK2;
        const int k2   = (t + 2) * BK2;
        const bool nx1 = (t + 1 < NT2);
        const bool nx2 = (t + 2 < NT2);

        // ---- phase 0: QUAD(0,0) [af=A0(t), bf01(t) pre-read]; stage A-m1(t+1)
        if (nx1) { STAGE_A(nbuf, 64, k1); STAGE_A(nbuf, 192, k1); }
        BAR();
        QUAD(0, 0, af, bf01);
        SCHED0();
        if (nx1) { VMC(6); } else { VMC(0); }
        BAR(); SCHED0();

        // ---- phase 1: read B23(t); QUAD(0,1); late-read A1(t); stage B-n1(t+1)
        #pragma unroll
        for (int ni = 0; ni < 2; ++ni) {
            bf23[ni][0] = RD16(buf + brow + (2 + ni) * 2048 + cA0);
            bf23[ni][1] = RD16(buf + brow + (2 + ni) * 2048 + cA1);
        }
        if (nx1) { STAGE_B(nbuf, 0, 1, k1); STAGE_B(nbuf, 1, 1, k1); }
        BAR();
        QUAD(0, 1, af, bf23);
        SCHED0();
        #pragma unroll
        for (int mi = 0; mi < 4; ++mi) {       // A1(t) into af (A0 dead)
            af[mi][0] = RD16(buf + arow + 8192 + mi * 2048 + cA0);
            af[mi][1] = RD16(buf + arow + 8192 + mi * 2048 + cA1);
        }
        if (nx1) { VMC(4); }
        BAR(); SCHED0();

        // ---- phase 2: QUAD(1,0) [af=A1]; late-read B01(t+1); stage A-m0(t+2)
        if (nx2) { STAGE_A(buf, 0, k2); STAGE_A(buf, 128, k2); }
        BAR();
        QUAD(1, 0, af, bf01);
        SCHED0();
        if (nx1) {
            #pragma unroll
            for (int ni = 0; ni < 2; ++ni) {   // B01(t+1) into bf01 (dead)
                bf01[ni][0] = RD16(nbuf + brow + ni * 2048 + cA0);
                bf01[ni][1] = RD16(nbuf + brow + ni * 2048 + cA1);
            }
        }
        BAR(); SCHED0();

        // ---- phase 3: QUAD(1,1); late-read A0(t+1); stage B-n0(t+2)
        if (nx2) { STAGE_B(buf, 0, 0, k2); STAGE_B(buf, 1, 0, k2); }
        BAR();
        QUAD(1, 1, af, bf23);
        SCHED0();
        if (nx1) {
            #pragma unroll
            for (int mi = 0; mi < 4; ++mi) {   // A0(t+1) into af (A1 dead)
                af[mi][0] = RD16(nbuf + arow + mi * 2048 + cA0);
                af[mi][1] = RD16(nbuf + arow + mi * 2048 + cA1);
            }
        }
        BAR(); SCHED0();
    }

    // ---- Epilogue: scale + bias, f32 store. C/D: col=fr, row=fq*4+j. ----
    const int gnBase = gN + wc * 64;
    const int gmBase = gM + wr * 128;
    #pragma unroll
    for (int n = 0; n < 4; ++n) {
        const int gn = gnBase + n * 16 + fr;
        const float sc = Sc[gn];
        const float bi = Bi[gn];
        #pragma unroll
        for (int m = 0; m < 8; ++m) {
            const int gm0 = gmBase + m * 16 + fq * 4;
            #pragma unroll
            for (int j = 0; j < 4; ++j)
                Out[(size_t)(gm0 + j) * N_DIM + gn] = acc[m][n][j] * sc + bi;
        }
    }
}

// ---------------- fallback: fused 128x128 (round-2, proven) ----------------
extern "C" __global__ __launch_bounds__(256)
void wq8_gemm_fused(const float* __restrict__ X,
                    const int* __restrict__ Wq,
                    const float* __restrict__ Sc,
                    const float* __restrict__ Bi,
                    float* __restrict__ Out)
{
    __shared__ __hip_bfloat16 As[BM][BK];
    __shared__ __hip_bfloat16 Bs[BN][BK];

    const int tid = threadIdx.x;
    const int w   = tid >> 6;
    const int l   = tid & 63;
    const int wr  = w >> 1;
    const int wc  = w & 1;
    const int fr  = l & 15;
    const int fq  = l >> 4;

    const int ntn  = N_DIM / BN;
    const int nwg  = (M_DIM / BM) * ntn;
    const int bid  = (int)blockIdx.x;
    const int wgid = (bid & 7) * (nwg >> 3) + (bid >> 3);
    const int g    = wgid / (8 * ntn);
    const int rr   = wgid % (8 * ntn);
    const int tm   = g * 8 + (rr & 7);
    const int tn   = rr >> 3;

    const int srow = tid >> 3;
    const int scol = (tid & 7) * 4;
    const float* a_g = X  + (size_t)(tm * BM + srow) * K_DIM + scol;
    const int*   b_g = Wq + (size_t)(tn * BN + srow) * K_DIM + scol;

    f32x4 acc[4][4];
    #pragma unroll
    for (int m = 0; m < 4; ++m)
        #pragma unroll
        for (int n = 0; n < 4; ++n)
            acc[m][n] = (f32x4)0.0f;

    for (int kt = 0; kt < K_DIM / BK; ++kt) {
        const int kofs = kt * BK;
        f32x4 xa[4];
        i32x4 wv[4];
        #pragma unroll
        for (int q = 0; q < 4; ++q)
            xa[q] = *(const f32x4*)(a_g + (size_t)q * 32 * K_DIM + kofs);
        #pragma unroll
        for (int q = 0; q < 4; ++q)
            wv[q] = *(const i32x4*)(b_g + (size_t)q * 32 * K_DIM + kofs);

        uint2 ap[4], bp[4];
        #pragma unroll
        for (int q = 0; q < 4; ++q) {
            ap[q] = pack4_bf16(xa[q].x, xa[q].y, xa[q].z, xa[q].w);
            bp[q] = pack4_bf16((float)wv[q].x, (float)wv[q].y,
                               (float)wv[q].z, (float)wv[q].w);
        }

        __syncthreads();
        #pragma unroll
        for (int q = 0; q < 4; ++q) {
            *(uint2*)(&As[q * 32 + srow][scol]) = ap[q];
            *(uint2*)(&Bs[q * 32 + srow][scol]) = bp[q];
        }
        __syncthreads();

        bf16x8 af[4], bfr[4];
        #pragma unroll
        for (int m = 0; m < 4; ++m)
            af[m] = *(const bf16x8*)(&As[wr * 64 + m * 16 + fr][fq * 8]);
        #pragma unroll
        for (int n = 0; n < 4; ++n)
            bfr[n] = *(const bf16x8*)(&Bs[wc * 64 + n * 16 + fr][fq * 8]);
        #pragma unroll
        for (int m = 0; m < 4; ++m)
            #pragma unroll
            for (int n = 0; n < 4; ++n)
                acc[m][n] = __builtin_amdgcn_mfma_f32_16x16x32_bf16(
                    af[m], bfr[n], acc[m][n], 0, 0, 0);
    }

    const int n_base = tn * BN + wc * 64;
    const int m_base = tm * BM + wr * 64;
    #pragma unroll
    for (int n = 0; n < 4; ++n) {
        const int gn = n_base + n * 16 + fr;
        const float sc = Sc[gn];
        const float bi = Bi[gn];
        #pragma unroll
        for (int m = 0; m < 4; ++m) {
            const int gm0 = m_base + m * 16 + fq * 4;
            #pragma unroll
            for (int j = 0; j < 4; ++j)
                Out[(size_t)(gm0 + j) * N_DIM + gn] = acc[m][n][j] * sc + bi;
        }
    }
}

extern "C" void kernel_launch(void* const* d_in, const int* in_sizes, int n_in,
                              void* d_out, int out_size, void* d_ws, size_t ws_size,
                              hipStream_t stream) {
    const float* X  = (const float*)d_in[0];
    const int*   Wq = (const int*)d_in[1];
    const float* Sc = (const float*)d_in[2];
    const float* Bi = (const float*)d_in[3];
    float*      Out = (float*)d_out;

    const size_t nX = (size_t)M_DIM * K_DIM;
    const size_t nW = (size_t)N_DIM * K_DIM;
    const size_t ws_needed = (nX + nW) * sizeof(ushort);   // 157.3 MB

    if (ws_size >= ws_needed) {
        ushort* Xb = (ushort*)d_ws;
        ushort* Wb = Xb + nX;
        cvt_x_bf16<<<2048, 256, 0, stream>>>(X, Xb, (int)(nX / 8));
        cvt_w_bf16<<<2048, 256, 0, stream>>>(Wq, Wb, (int)(nW / 8));
        dim3 grid2((M_DIM / BM2) * (N_DIM / BN2));   // 1376
        wq8_gemm_256<<<grid2, 512, 0, stream>>>(Xb, Wb, Sc, Bi, Out);
    } else {
        dim3 grid((M_DIM / BM) * (N_DIM / BN));      // 5504
        wq8_gemm_fused<<<grid, 256, 0, stream>>>(X, Wq, Sc, Bi, Out);
    }
}